// Round 1
// baseline (327.603 us; speedup 1.0000x reference)
//
#include <hip/hip_runtime.h>
#include <hip/hip_bf16.h>

#define N_PATHS   10000000
#define MAX_LEN   3
#define N_NODES_C 100000
#define HIDDEN    128

// Kernel 1: proj[l * n_nodes + node] = dot(node_feature[node, :], W[l, 0, :])
// One wave (64 lanes) per node; lane i holds float2 = elements {2i, 2i+1}.
__global__ __launch_bounds__(256) void proj_kernel(
    const float* __restrict__ feat,   // (n_nodes, 128)
    const float* __restrict__ W,      // (3, 1, 128)
    float* __restrict__ proj,         // (3, n_nodes)
    int n_nodes)
{
    int gtid = blockIdx.x * blockDim.x + threadIdx.x;
    int node = gtid >> 6;
    int lane = threadIdx.x & 63;
    if (node >= n_nodes) return;

    const float2* f2 = (const float2*)(feat + (size_t)node * HIDDEN);
    const float2* w2 = (const float2*)W;

    float2 f  = f2[lane];
    float2 w0 = w2[lane];           // W[0]
    float2 w1 = w2[64 + lane];      // W[1]
    float2 w2v = w2[128 + lane];    // W[2]

    float s0 = f.x * w0.x  + f.y * w0.y;
    float s1 = f.x * w1.x  + f.y * w1.y;
    float s2 = f.x * w2v.x + f.y * w2v.y;

    #pragma unroll
    for (int off = 32; off > 0; off >>= 1) {
        s0 += __shfl_xor(s0, off, 64);
        s1 += __shfl_xor(s1, off, 64);
        s2 += __shfl_xor(s2, off, 64);
    }

    if (lane == 0) {
        proj[0 * n_nodes + node] = s0;
        proj[1 * n_nodes + node] = s1;
        proj[2 * n_nodes + node] = s2;
    }
}

// Kernel 2: one thread handles 4 paths (12 ints = 3 aligned int4 loads),
// gathers from the L2-resident proj planes, writes one float4.
__global__ __launch_bounds__(256) void score_kernel(
    const int* __restrict__ paths,    // (n_paths, 3) int32
    const float* __restrict__ proj,   // (3, n_nodes)
    float* __restrict__ out,          // (n_paths,)
    int n_nodes, int n_quads)
{
    int t = blockIdx.x * blockDim.x + threadIdx.x;
    if (t >= n_quads) return;

    const int4* p4 = (const int4*)paths;
    int4 a = p4[3 * t + 0];
    int4 b = p4[3 * t + 1];
    int4 c = p4[3 * t + 2];

    int ids[12] = { a.x, a.y, a.z, a.w,
                    b.x, b.y, b.z, b.w,
                    c.x, c.y, c.z, c.w };

    float4 o;
    float* op = &o.x;
    #pragma unroll
    for (int j = 0; j < 4; ++j) {
        float s = 0.0f;
        int cnt = 0;
        #pragma unroll
        for (int l = 0; l < 3; ++l) {
            int id = ids[j * 3 + l];
            if (id >= 0 && id < n_nodes) {   // valid hop (guard also protects vs dtype surprises)
                s += proj[l * n_nodes + id];
                cnt += 1;
            }
        }
        op[j] = s / (float)(cnt > 0 ? cnt : 1);
    }
    ((float4*)out)[t] = o;
}

extern "C" void kernel_launch(void* const* d_in, const int* in_sizes, int n_in,
                              void* d_out, int out_size, void* d_ws, size_t ws_size,
                              hipStream_t stream) {
    const int*   paths = (const int*)d_in[0];     // (N_PATHS, 3) int32
    const float* feat  = (const float*)d_in[1];   // (N_NODES, 128) f32
    const float* W     = (const float*)d_in[2];   // (3, 1, 128) f32
    float*       out   = (float*)d_out;           // (N_PATHS,) f32

    const int n_nodes = in_sizes[1] / HIDDEN;     // 100000
    float* proj = (float*)d_ws;                   // 3 * n_nodes floats = 1.2 MB

    // Kernel 1: 1 wave per node, 4 waves per 256-thread block.
    {
        int blocks = (n_nodes + 3) / 4;
        proj_kernel<<<blocks, 256, 0, stream>>>(feat, W, proj, n_nodes);
    }

    // Kernel 2: 1 thread per 4 paths.
    {
        int n_quads = N_PATHS / 4;                // 2,500,000
        int blocks = (n_quads + 255) / 256;
        score_kernel<<<blocks, 256, 0, stream>>>(paths, proj, out, n_nodes, n_quads);
    }
}